// Round 9
// baseline (258.791 us; speedup 1.0000x reference)
//
#include <hip/hip_runtime.h>

// CrossAttentionPro on MI355X — Round 8:
//  R7 rank-64 pipeline +
//  + flash_both: both flash attentions in ONE launch (1024 blocks, parity-
//    interleaved) -> 4 blocks/CU; flash<1> writes raw cval_x2y (DH2), diff
//    moved to a tiny diff_k kernel (DH = DH2 - CV2).
//  + LDS 50->32 KB: Ps overlaid on dead Ks region (extra barrier after QK),
//    P processed in two 64-col halves; Ps row stride 72 halfs (16B-aligned,
//    phase-uniform banks).
//  + prep kernel fuses 4 f32->f16 converts + mask bit-packing (13->8 launches).

typedef _Float16 half_t;
typedef _Float16 half8 __attribute__((ext_vector_type(8)));
typedef _Float16 half4v __attribute__((ext_vector_type(4)));
typedef float floatx4 __attribute__((ext_vector_type(4)));

constexpr int Bc = 2, Tc = 2048, Mc = 1024, Cc = 512, Hc = 8, Dc = 64;
constexpr long BTC = (long)Bc * Tc * Cc;

enum { EPI_F16STORE = 0, EPI_QKV_X = 1, EPI_QKV_Y = 2, EPI_PROJ = 3 };

struct EpiParams {
  half_t* h0;
  half_t* h1;
  half_t* h2;
  half_t* h3;
  float* f0;
  const float* bias;
  float scale;
  int ldc;
  long bstride;
  int seq;
};

// async global->LDS, 16B per lane; dst must be wave-uniform base + lane*16.
__device__ __forceinline__ void gld_lds16(const half_t* g, half_t* l) {
  __builtin_amdgcn_global_load_lds(
      (const __attribute__((address_space(1))) void*)g,
      (__attribute__((address_space(3))) void*)l, 16, 0, 0);
}

// ---------------------------------------------------------------- GEMM (NT)
// R2-proven: C[r,c] = sum_k A[r,k]*Bt[c,k], BK=32 swizzled async staging
// (measured 0 bank conflicts), direct per-element epilogue.
template <int BM, int BN, int WMG, int WNG, int EPI>
__global__ __launch_bounds__(256) void gemm_nt(
    const half_t* __restrict__ A, const half_t* __restrict__ Bt,
    int K, int lda, int ldb, long bsA, long bsB, EpiParams ep)
{
  constexpr int BK = 32;
  constexpr int WTM = BM / WMG, WTN = BN / WNG;
  constexpr int MI = WTM / 16, NI = WTN / 16;
  constexpr int ACHUNKS = BM * 4;
  constexpr int BCHUNKS = BN * 4;
  __shared__ __align__(16) half_t As[BM * BK];
  __shared__ __align__(16) half_t Bs[BN * BK];

  const int tid = threadIdx.x;
  const int lane = tid & 63;
  const int wave = tid >> 6;
  const int wm = wave / WNG, wn = wave % WNG;
  const int r16 = lane & 15, g = lane >> 4;
  const int z = blockIdx.z;
  const long m0 = (long)blockIdx.y * BM;
  const long n0 = (long)blockIdx.x * BN;
  const half_t* Abase = A + (long)z * bsA + m0 * (long)lda;
  const half_t* Bbase = Bt + (long)z * bsB + n0 * (long)ldb;

  const int rA = wm * WTM + r16;
  const int rB = wn * WTN + r16;
  const int swA = (g ^ ((rA >> 1) & 3)) * 8;
  const int swB = (g ^ ((rB >> 1) & 3)) * 8;

  floatx4 acc[MI][NI];
#pragma unroll
  for (int mi = 0; mi < MI; ++mi)
#pragma unroll
    for (int ni = 0; ni < NI; ++ni)
      acc[mi][ni] = floatx4{0.f, 0.f, 0.f, 0.f};

  for (int kt = 0; kt < K; kt += BK) {
#pragma unroll
    for (int i = 0; i < (ACHUNKS + 255) / 256; ++i) {
      const int c = tid + i * 256;
      if (ACHUNKS % 256 == 0 || c < ACHUNKS) {
        const int row = c >> 2, js = c & 3;
        const int jg = js ^ ((row >> 1) & 3);
        gld_lds16(Abase + (long)row * lda + kt + jg * 8, As + c * 8);
      }
    }
#pragma unroll
    for (int i = 0; i < (BCHUNKS + 255) / 256; ++i) {
      const int c = tid + i * 256;
      if (BCHUNKS % 256 == 0 || c < BCHUNKS) {
        const int row = c >> 2, js = c & 3;
        const int jg = js ^ ((row >> 1) & 3);
        gld_lds16(Bbase + (long)row * ldb + kt + jg * 8, Bs + c * 8);
      }
    }
    __syncthreads();
    half8 aF[MI], bF[NI];
#pragma unroll
    for (int mi = 0; mi < MI; ++mi)
      aF[mi] = *reinterpret_cast<const half8*>(&As[(rA + mi * 16) * BK + swA]);
#pragma unroll
    for (int ni = 0; ni < NI; ++ni)
      bF[ni] = *reinterpret_cast<const half8*>(&Bs[(rB + ni * 16) * BK + swB]);
#pragma unroll
    for (int mi = 0; mi < MI; ++mi)
#pragma unroll
      for (int ni = 0; ni < NI; ++ni)
        acc[mi][ni] = __builtin_amdgcn_mfma_f32_16x16x32_f16(aF[mi], bF[ni], acc[mi][ni], 0, 0, 0);
    __syncthreads();
  }

  // epilogue: C/D layout col=lane&15, row=(lane>>4)*4+reg  [m89-verified]
#pragma unroll
  for (int mi = 0; mi < MI; ++mi) {
#pragma unroll
    for (int ni = 0; ni < NI; ++ni) {
#pragma unroll
      for (int reg = 0; reg < 4; ++reg) {
        const int r = (int)m0 + wm * WTM + mi * 16 + g * 4 + reg;
        const int c = (int)n0 + wn * WTN + ni * 16 + r16;
        const float v = acc[mi][ni][reg];
        if constexpr (EPI == EPI_F16STORE) {
          ep.h0[(long)z * ep.bstride + (long)r * ep.ldc + c] = (half_t)(v * ep.scale);
        } else if constexpr (EPI == EPI_QKV_X) {
          const float val = v + ep.bias[c];
          const int which = c >> 9;     // 0=q 1=k 2=v
          const int cc2 = c & 511;
          const int h = cc2 >> 6, d = cc2 & 63;
          const int b = r / ep.seq, t = r - b * ep.seq;
          const long bh = (long)(b * Hc + h);
          if (which == 0)      ep.h0[(bh * ep.seq + t) * Dc + d] = (half_t)(val * 0.125f); // QXs
          else if (which == 1) ep.h1[(bh * ep.seq + t) * Dc + d] = (half_t)val;            // KX
          else                 ep.h2[(bh * Dc + d) * ep.seq + t] = (half_t)val;            // VXT
        } else if constexpr (EPI == EPI_QKV_Y) {
          const float val = v + ep.bias[c];
          const int which = c >> 9;
          const int cc2 = c & 511;
          const int h = cc2 >> 6, d = cc2 & 63;
          const int b = r / ep.seq, t = r - b * ep.seq;
          const long bh = (long)(b * Hc + h);
          if (which == 0)      ep.h0[(bh * Dc + d) * ep.seq + t] = (half_t)(val * 0.125f); // QYTs
          else if (which == 1) { ep.h1[(bh * ep.seq + t) * Dc + d] = (half_t)val;          // KY
                                 ep.h3[(bh * Dc + d) * ep.seq + t] = (half_t)val; }        // KYT
          else                 ep.h2[(bh * Dc + d) * ep.seq + t] = (half_t)val;            // VYT
        } else {  // EPI_PROJ
          ep.f0[(long)r * Cc + c] = v + ep.bias[c];
        }
      }
    }
  }
}

// --------------------------------------------------------- flash body
// Standard flash, D=64, QT=64 q-rows/block, s-tiles of 128.
// LDS: uni[8192] = Ks (staging) UNION Ps (per-wave slab w*1152, row
// stride 72 halfs — 16B-aligned, phase-uniform banks); Vb[8192] = V^T.
// Ks dead after QK -> barrier -> Ps overlay; P done in two 64-col halves.
// z-local XCD swizzle: z = ((bb&7)<<1)|(sIdx&1) -> K/V L2-resident.
template <bool MASKED>
__device__ __forceinline__ void flash_body(
    const half_t* __restrict__ Qp, const half_t* __restrict__ Kp,
    const half_t* __restrict__ Vp, const unsigned char* __restrict__ mpk,
    half_t* __restrict__ outp, int Slen, int bb,
    half_t* uni, half_t* Vb)
{
  const int tid = threadIdx.x, lane = tid & 63, w = tid >> 6;
  const int r16 = lane & 15, g = lane >> 4;
  const int sIdx = bb >> 3;
  const int z = ((bb & 7) << 1) | (sIdx & 1);
  const int q0 = (sIdx >> 1) * 64;
  const int b = z >> 3, h = z & 7;
  const int NT = Slen >> 7;
  const half_t* Qz = Qp + ((long)z * Tc + q0) * 64;
  const half_t* Kz = Kp + (long)z * Slen * 64;
  const half_t* Vz = Vp + (long)z * 64 * Slen;
  half_t* Ps = uni + w * 1152;   // 16 rows x 72

  const half8 aQ0 = *reinterpret_cast<const half8*>(Qz + (w * 16 + r16) * 64 + g * 8);
  const half8 aQ1 = *reinterpret_cast<const half8*>(Qz + (w * 16 + r16) * 64 + 32 + g * 8);

  floatx4 oacc[4];
#pragma unroll
  for (int no = 0; no < 4; ++no) oacc[no] = floatx4{0.f, 0.f, 0.f, 0.f};
  float mrun[4], lrun[4];
#pragma unroll
  for (int reg = 0; reg < 4; ++reg) { mrun[reg] = -1e30f; lrun[reg] = 0.f; }

  for (int s0 = 0; s0 < Slen; s0 += 128) {
    // stage K: 128 rows x 64 halfs into uni, slot js holds chunk js^(row&7)
#pragma unroll
    for (int i = 0; i < 4; ++i) {
      const int c = tid + i * 256;
      const int row = c >> 3, js = c & 7;
      const int jg = js ^ (row & 7);
      gld_lds16(Kz + (long)(s0 + row) * 64 + jg * 8, uni + c * 8);
    }
    // stage V^T: 64 rows x 128 halfs, slot js holds js^(row&15)
#pragma unroll
    for (int i = 0; i < 4; ++i) {
      const int c = tid + i * 256;
      const int row = c >> 4, js = c & 15;
      const int jg = js ^ (row & 15);
      gld_lds16(Vz + (long)row * Slen + s0 + jg * 8, Vb + c * 8);
    }
    unsigned int mb[4];
    if constexpr (MASKED) {
      const int tile = s0 >> 7;
#pragma unroll
      for (int reg = 0; reg < 4; ++reg) {
        const int t = q0 + w * 16 + g * 4 + reg;
        mb[reg] = mpk[((long)t * NT + tile) * 16 + r16];
      }
    }
    __syncthreads();

    // S = Q K^T  (K-dim 64 = 2 MFMA steps per ni)
    floatx4 sacc[8];
#pragma unroll
    for (int ni = 0; ni < 8; ++ni) sacc[ni] = floatx4{0.f, 0.f, 0.f, 0.f};
#pragma unroll
    for (int ni = 0; ni < 8; ++ni) {
      const int rB = ni * 16 + r16;
      const half8 b0 = *reinterpret_cast<const half8*>(&uni[rB * 64 + ((g) ^ (rB & 7)) * 8]);
      sacc[ni] = __builtin_amdgcn_mfma_f32_16x16x32_f16(aQ0, b0, sacc[ni], 0, 0, 0);
      const half8 b1 = *reinterpret_cast<const half8*>(&uni[rB * 64 + ((4 + g) ^ (rB & 7)) * 8]);
      sacc[ni] = __builtin_amdgcn_mfma_f32_16x16x32_f16(aQ1, b1, sacc[ni], 0, 0, 0);
    }
    __syncthreads();   // Ks dead -> uni becomes Ps

    // mask + running max (C-layout: row=g*4+reg, col=ni*16+r16) [R4-verified]
    float sv[8][4];
#pragma unroll
    for (int ni = 0; ni < 8; ++ni)
#pragma unroll
      for (int reg = 0; reg < 4; ++reg) sv[ni][reg] = sacc[ni][reg];
    if constexpr (MASKED) {
#pragma unroll
      for (int reg = 0; reg < 4; ++reg)
#pragma unroll
        for (int ni = 0; ni < 8; ++ni)
          if (!((mb[reg] >> ni) & 1)) sv[ni][reg] = -__builtin_inff();
    }
    float al[4], psum[4];
#pragma unroll
    for (int reg = 0; reg < 4; ++reg) {
      float tm = sv[0][reg];
#pragma unroll
      for (int ni = 1; ni < 8; ++ni) tm = fmaxf(tm, sv[ni][reg]);
      tm = fmaxf(tm, __shfl_xor(tm, 1));
      tm = fmaxf(tm, __shfl_xor(tm, 2));
      tm = fmaxf(tm, __shfl_xor(tm, 4));
      tm = fmaxf(tm, __shfl_xor(tm, 8));
      const float mnew = fmaxf(mrun[reg], tm);
      al[reg] = __expf(mrun[reg] - mnew);
      mrun[reg] = mnew;
      psum[reg] = 0.f;
#pragma unroll
      for (int no = 0; no < 4; ++no) oacc[no][reg] *= al[reg];
    }

    // exp + P-write + PV, two 64-col halves (Ps slab wave-private; DS in-order)
#pragma unroll
    for (int hf = 0; hf < 2; ++hf) {
#pragma unroll
      for (int reg = 0; reg < 4; ++reg)
#pragma unroll
        for (int ni = 0; ni < 4; ++ni) {
          const float e = __expf(sv[hf * 4 + ni][reg] - mrun[reg]);
          psum[reg] += e;
          Ps[(g * 4 + reg) * 72 + ni * 16 + r16] = (half_t)e;
        }
#pragma unroll
      for (int ks2 = 0; ks2 < 2; ++ks2) {
        const half8 aP = *reinterpret_cast<const half8*>(&Ps[r16 * 72 + ks2 * 32 + g * 8]);
#pragma unroll
        for (int no = 0; no < 4; ++no) {
          const int rV = no * 16 + r16;
          const half8 bV = *reinterpret_cast<const half8*>(
              &Vb[rV * 128 + (((hf * 2 + ks2) * 4 + g) ^ (rV & 15)) * 8]);
          oacc[no] = __builtin_amdgcn_mfma_f32_16x16x32_f16(aP, bV, oacc[no], 0, 0, 0);
        }
      }
    }
#pragma unroll
    for (int reg = 0; reg < 4; ++reg) {
      float ps = psum[reg];
      ps += __shfl_xor(ps, 1);
      ps += __shfl_xor(ps, 2);
      ps += __shfl_xor(ps, 4);
      ps += __shfl_xor(ps, 8);
      lrun[reg] = lrun[reg] * al[reg] + ps;
    }
    __syncthreads();   // Ps/Vb reads done -> restage
  }

  // epilogue: O/l -> out[b, t, h*64+d]
#pragma unroll
  for (int reg = 0; reg < 4; ++reg) {
    const float linv = 1.f / lrun[reg];
    const int t = q0 + w * 16 + g * 4 + reg;
#pragma unroll
    for (int no = 0; no < 4; ++no) {
      const int d = no * 16 + r16;
      outp[((long)(b * Tc + t)) * Cc + h * 64 + d] = (half_t)(oacc[no][reg] * linv);
    }
  }
}

// Both attentions in one launch, parity-interleaved.
__global__ __launch_bounds__(256) void flash_both(
    const half_t* __restrict__ Q2, const half_t* __restrict__ KX,
    const half_t* __restrict__ VXT, const unsigned char* __restrict__ mpk,
    half_t* __restrict__ CV2,
    const half_t* __restrict__ QX, const half_t* __restrict__ KY,
    const half_t* __restrict__ VYT, half_t* __restrict__ DH2)
{
  __shared__ __align__(16) half_t uni[8192];
  __shared__ __align__(16) half_t Vb[8192];
  const int bx = blockIdx.x;
  if ((bx & 1) == 0)
    flash_body<true>(Q2, KX, VXT, mpk, CV2, Tc, bx >> 1, uni, Vb);
  else
    flash_body<false>(QX, KY, VYT, nullptr, DH2, Mc, bx >> 1, uni, Vb);
}

// ----------------------------------------------- prep: converts + mask pack
__device__ __forceinline__ void cvt4(const float* in, half_t* out, long i) {
  const float4 f = reinterpret_cast<const float4*>(in)[i];
  half4v h; h[0] = (half_t)f.x; h[1] = (half_t)f.y; h[2] = (half_t)f.z; h[3] = (half_t)f.w;
  reinterpret_cast<half4v*>(out)[i] = h;
}

__global__ __launch_bounds__(256) void prep(
    const float* __restrict__ x, const float* __restrict__ y,
    const float* __restrict__ qw, const float* __restrict__ pw,
    const int* __restrict__ mask,
    half_t* __restrict__ XH, half_t* __restrict__ YH,
    half_t* __restrict__ WQ, half_t* __restrict__ WP,
    unsigned char* __restrict__ mpk)
{
  const long i = (long)blockIdx.x * 256 + threadIdx.x;
  constexpr long n0 = 524288;            // x/4
  constexpr long n1 = n0 + 262144;       // y/4
  constexpr long n2 = n1 + 196608;       // qkv_w/4
  constexpr long n3 = n2 + 65536;        // proj_w/4
  if (i < n0) cvt4(x, XH, i);
  else if (i < n1) cvt4(y, YH, i - n0);
  else if (i < n2) cvt4(qw, WQ, i - n1);
  else if (i < n3) cvt4(pw, WP, i - n2);
  else {
    const long idx = i - n3;             // [0, Tc*256)
    const int t = (int)(idx >> 8), tile = (int)((idx >> 4) & 15), r16 = (int)(idx & 15);
    const int* row = mask + (long)t * Tc + tile * 128 + r16;
    unsigned int bbits = 0;
#pragma unroll
    for (int ni = 0; ni < 8; ++ni)
      bbits |= (row[ni * 16] != 0 ? 1u : 0u) << ni;
    mpk[idx] = (unsigned char)bbits;
  }
}

// ------------------------------------------------------- DH = DH2 - CV2
__global__ __launch_bounds__(256) void diff_k(
    const half_t* __restrict__ a, const half_t* __restrict__ b,
    half_t* __restrict__ o)
{
  const long i = (long)blockIdx.x * 256 + threadIdx.x;
  const half8 va = reinterpret_cast<const half8*>(a)[i];
  const half8 vb = reinterpret_cast<const half8*>(b)[i];
  reinterpret_cast<half8*>(o)[i] = va - vb;
}

// ------------------------------------------------------------- workspace map
constexpr size_t OFF_XH   = 0;                                   // [B*T,C] f16
constexpr size_t OFF_YH   = OFF_XH   + (size_t)Bc*Tc*Cc*2;
constexpr size_t OFF_WQ   = OFF_YH   + (size_t)Bc*Mc*Cc*2;
constexpr size_t OFF_WP   = OFF_WQ   + (size_t)3*Cc*Cc*2;
constexpr size_t OFF_QX   = OFF_WP   + (size_t)Cc*Cc*2;          // [z,T,D] scaled
constexpr size_t OFF_KX   = OFF_QX   + (size_t)Bc*Hc*Tc*Dc*2;    // [z,T,D]
constexpr size_t OFF_VXT  = OFF_KX   + (size_t)Bc*Hc*Tc*Dc*2;    // [z,D,T]
constexpr size_t OFF_QYT  = OFF_VXT  + (size_t)Bc*Hc*Tc*Dc*2;    // [z,D,M] scaled
constexpr size_t OFF_KY   = OFF_QYT  + (size_t)Bc*Hc*Mc*Dc*2;    // [z,M,D]
constexpr size_t OFF_KYT  = OFF_KY   + (size_t)Bc*Hc*Mc*Dc*2;    // [z,D,M]
constexpr size_t OFF_VYT  = OFF_KYT  + (size_t)Bc*Hc*Mc*Dc*2;    // [z,D,M]
constexpr size_t OFF_WT   = OFF_VYT  + (size_t)Bc*Hc*Mc*Dc*2;    // [z,64,64]
constexpr size_t OFF_Q2   = OFF_WT   + (size_t)Bc*Hc*Dc*Dc*2;    // [z,T,D]
constexpr size_t OFF_CV2  = OFF_Q2   + (size_t)Bc*Hc*Tc*Dc*2;    // [B,T,C]
constexpr size_t OFF_DH2  = OFF_CV2  + (size_t)Bc*Tc*Cc*2;       // [B,T,C] raw cval_x2y
constexpr size_t OFF_DH   = OFF_DH2  + (size_t)Bc*Tc*Cc*2;       // [B,T,C] diff
constexpr size_t OFF_MPK  = OFF_DH   + (size_t)Bc*Tc*Cc*2;       // [T,16,16] u8
// total ~54 MB

extern "C" void kernel_launch(void* const* d_in, const int* in_sizes, int n_in,
                              void* d_out, int out_size, void* d_ws, size_t ws_size,
                              hipStream_t stream) {
  const float* x      = (const float*)d_in[0];
  const float* y      = (const float*)d_in[1];
  const int*   mask   = (const int*)  d_in[2];
  const float* qkv_b  = (const float*)d_in[4];
  const float* proj_b = (const float*)d_in[6];
  float* out = (float*)d_out;
  char* ws = (char*)d_ws;

  half_t* XH   = (half_t*)(ws + OFF_XH);
  half_t* YH   = (half_t*)(ws + OFF_YH);
  half_t* WQ   = (half_t*)(ws + OFF_WQ);
  half_t* WP   = (half_t*)(ws + OFF_WP);
  half_t* QX   = (half_t*)(ws + OFF_QX);
  half_t* KX   = (half_t*)(ws + OFF_KX);
  half_t* VXT  = (half_t*)(ws + OFF_VXT);
  half_t* QYT  = (half_t*)(ws + OFF_QYT);
  half_t* KY   = (half_t*)(ws + OFF_KY);
  half_t* KYT  = (half_t*)(ws + OFF_KYT);
  half_t* VYT  = (half_t*)(ws + OFF_VYT);
  half_t* WT   = (half_t*)(ws + OFF_WT);
  half_t* Q2   = (half_t*)(ws + OFF_Q2);
  half_t* CV2  = (half_t*)(ws + OFF_CV2);
  half_t* DH2  = (half_t*)(ws + OFF_DH2);
  half_t* DH   = (half_t*)(ws + OFF_DH);
  unsigned char* MPK = (unsigned char*)(ws + OFF_MPK);

  // converts + mask packing (one launch)
  prep<<<6144, 256, 0, stream>>>(x, y, (const float*)d_in[3], (const float*)d_in[5],
                                 mask, XH, YH, WQ, WP, MPK);

  // qkv projections
  {
    EpiParams ep{}; ep.h0 = QX; ep.h1 = KX; ep.h2 = VXT; ep.bias = qkv_b; ep.seq = Tc;
    gemm_nt<128,128,2,2,EPI_QKV_X><<<dim3(12, 32, 1), 256, 0, stream>>>(
        XH, WQ, Cc, Cc, Cc, 0, 0, ep);
  }
  {
    EpiParams ep{}; ep.h0 = QYT; ep.h1 = KY; ep.h2 = VYT; ep.h3 = KYT;
    ep.bias = qkv_b; ep.seq = Mc;
    gemm_nt<64,128,2,2,EPI_QKV_Y><<<dim3(12, 32, 1), 256, 0, stream>>>(
        YH, WQ, Cc, Cc, Cc, 0, 0, ep);
  }

  // WT[z][d2][d1] = 0.125 * sum_m QYTs[d2,m] KYT[d1,m]  (total scale^3)
  {
    EpiParams ep{}; ep.h0 = WT; ep.scale = 0.125f; ep.ldc = 64; ep.bstride = 64 * 64;
    gemm_nt<64,64,2,2,EPI_F16STORE><<<dim3(1, 1, Bc*Hc), 256, 0, stream>>>(
        QYT, KYT, Mc, Mc, Mc, (long)Dc*Mc, (long)Dc*Mc, ep);
  }
  // Q2[z][t][d2] = sum_d1 QXs[t,d1] WT[d2,d1]
  {
    EpiParams ep{}; ep.h0 = Q2; ep.scale = 1.f; ep.ldc = 64; ep.bstride = (long)Tc * 64;
    gemm_nt<128,64,2,2,EPI_F16STORE><<<dim3(1, Tc/128, Bc*Hc), 256, 0, stream>>>(
        QX, WT, Dc, Dc, Dc, (long)Tc*Dc, (long)64*64, ep);
  }

  // both attentions, one launch (parity-interleaved, 1024 blocks)
  flash_both<<<dim3(2 * (Tc/64) * Bc*Hc), 256, 0, stream>>>(
      Q2, KX, VXT, MPK, CV2, QX, KY, VYT, DH2);

  // DH = cval_x2y - cval_y2x
  diff_k<<<(int)(BTC/8/256), 256, 0, stream>>>(DH2, CV2, DH);

  // out = DH @ proj_w^T + proj_b
  {
    EpiParams ep{}; ep.f0 = out; ep.bias = proj_b;
    gemm_nt<128,64,2,2,EPI_PROJ><<<dim3(8, 32, 1), 256, 0, stream>>>(
        DH, WP, Cc, Cc, Cc, 0, 0, ep);
  }
}

// Round 10
// 244.971 us; speedup vs baseline: 1.0564x; 1.0564x over previous
//
#include <hip/hip_runtime.h>

// CrossAttentionPro on MI355X — Round 9:
//  R8 pipeline, flash restructured for the measured LDS-pipe bound:
//  + MI=2 (128 q-rows/block): K/V b128 reads + staging serve 2 MFMAs each
//  + row-sum via ones-MFMA (all-cols-equal trick) — kills psum shfls
//  + row-max via DPP row_ror reductions (VALU, not DS pipe)
// chained = Qx (scale^3 Ky^T Qy) Kx^T; both attentions standard D=64 flash.

typedef _Float16 half_t;
typedef _Float16 half8 __attribute__((ext_vector_type(8)));
typedef _Float16 half4v __attribute__((ext_vector_type(4)));
typedef float floatx4 __attribute__((ext_vector_type(4)));

constexpr int Bc = 2, Tc = 2048, Mc = 1024, Cc = 512, Hc = 8, Dc = 64;
constexpr long BTC = (long)Bc * Tc * Cc;

enum { EPI_F16STORE = 0, EPI_QKV_X = 1, EPI_QKV_Y = 2, EPI_PROJ = 3 };

struct EpiParams {
  half_t* h0;
  half_t* h1;
  half_t* h2;
  half_t* h3;
  float* f0;
  const float* bias;
  float scale;
  int ldc;
  long bstride;
  int seq;
};

// async global->LDS, 16B per lane; dst must be wave-uniform base + lane*16.
__device__ __forceinline__ void gld_lds16(const half_t* g, half_t* l) {
  __builtin_amdgcn_global_load_lds(
      (const __attribute__((address_space(1))) void*)g,
      (__attribute__((address_space(3))) void*)l, 16, 0, 0);
}

// max over each 16-lane row via DPP rotations (VALU pipe, no DS traffic).
__device__ __forceinline__ float rowmax16(float v) {
  union fi { float f; int i; };
#define RMAX_STEP(CTRL)                                                     \
  { fi a; a.f = v; fi b;                                                    \
    b.i = __builtin_amdgcn_update_dpp(a.i, a.i, CTRL, 0xf, 0xf, true);      \
    v = fmaxf(v, b.f); }
  RMAX_STEP(0x121)  // row_ror:1
  RMAX_STEP(0x122)  // row_ror:2
  RMAX_STEP(0x124)  // row_ror:4
  RMAX_STEP(0x128)  // row_ror:8
#undef RMAX_STEP
  return v;
}

// ---------------------------------------------------------------- GEMM (NT)
// R2-proven: C[r,c] = sum_k A[r,k]*Bt[c,k], BK=32 swizzled async staging
// (measured 0 bank conflicts), direct per-element epilogue.
template <int BM, int BN, int WMG, int WNG, int EPI>
__global__ __launch_bounds__(256) void gemm_nt(
    const half_t* __restrict__ A, const half_t* __restrict__ Bt,
    int K, int lda, int ldb, long bsA, long bsB, EpiParams ep)
{
  constexpr int BK = 32;
  constexpr int WTM = BM / WMG, WTN = BN / WNG;
  constexpr int MI = WTM / 16, NI = WTN / 16;
  constexpr int ACHUNKS = BM * 4;
  constexpr int BCHUNKS = BN * 4;
  __shared__ __align__(16) half_t As[BM * BK];
  __shared__ __align__(16) half_t Bs[BN * BK];

  const int tid = threadIdx.x;
  const int lane = tid & 63;
  const int wave = tid >> 6;
  const int wm = wave / WNG, wn = wave % WNG;
  const int r16 = lane & 15, g = lane >> 4;
  const int z = blockIdx.z;
  const long m0 = (long)blockIdx.y * BM;
  const long n0 = (long)blockIdx.x * BN;
  const half_t* Abase = A + (long)z * bsA + m0 * (long)lda;
  const half_t* Bbase = Bt + (long)z * bsB + n0 * (long)ldb;

  const int rA = wm * WTM + r16;
  const int rB = wn * WTN + r16;
  const int swA = (g ^ ((rA >> 1) & 3)) * 8;
  const int swB = (g ^ ((rB >> 1) & 3)) * 8;

  floatx4 acc[MI][NI];
#pragma unroll
  for (int mi = 0; mi < MI; ++mi)
#pragma unroll
    for (int ni = 0; ni < NI; ++ni)
      acc[mi][ni] = floatx4{0.f, 0.f, 0.f, 0.f};

  for (int kt = 0; kt < K; kt += BK) {
#pragma unroll
    for (int i = 0; i < (ACHUNKS + 255) / 256; ++i) {
      const int c = tid + i * 256;
      if (ACHUNKS % 256 == 0 || c < ACHUNKS) {
        const int row = c >> 2, js = c & 3;
        const int jg = js ^ ((row >> 1) & 3);
        gld_lds16(Abase + (long)row * lda + kt + jg * 8, As + c * 8);
      }
    }
#pragma unroll
    for (int i = 0; i < (BCHUNKS + 255) / 256; ++i) {
      const int c = tid + i * 256;
      if (BCHUNKS % 256 == 0 || c < BCHUNKS) {
        const int row = c >> 2, js = c & 3;
        const int jg = js ^ ((row >> 1) & 3);
        gld_lds16(Bbase + (long)row * ldb + kt + jg * 8, Bs + c * 8);
      }
    }
    __syncthreads();
    half8 aF[MI], bF[NI];
#pragma unroll
    for (int mi = 0; mi < MI; ++mi)
      aF[mi] = *reinterpret_cast<const half8*>(&As[(rA + mi * 16) * BK + swA]);
#pragma unroll
    for (int ni = 0; ni < NI; ++ni)
      bF[ni] = *reinterpret_cast<const half8*>(&Bs[(rB + ni * 16) * BK + swB]);
#pragma unroll
    for (int mi = 0; mi < MI; ++mi)
#pragma unroll
      for (int ni = 0; ni < NI; ++ni)
        acc[mi][ni] = __builtin_amdgcn_mfma_f32_16x16x32_f16(aF[mi], bF[ni], acc[mi][ni], 0, 0, 0);
    __syncthreads();
  }

  // epilogue: C/D layout col=lane&15, row=(lane>>4)*4+reg  [m89-verified]
#pragma unroll
  for (int mi = 0; mi < MI; ++mi) {
#pragma unroll
    for (int ni = 0; ni < NI; ++ni) {
#pragma unroll
      for (int reg = 0; reg < 4; ++reg) {
        const int r = (int)m0 + wm * WTM + mi * 16 + g * 4 + reg;
        const int c = (int)n0 + wn * WTN + ni * 16 + r16;
        const float v = acc[mi][ni][reg];
        if constexpr (EPI == EPI_F16STORE) {
          ep.h0[(long)z * ep.bstride + (long)r * ep.ldc + c] = (half_t)(v * ep.scale);
        } else if constexpr (EPI == EPI_QKV_X) {
          const float val = v + ep.bias[c];
          const int which = c >> 9;     // 0=q 1=k 2=v
          const int cc2 = c & 511;
          const int h = cc2 >> 6, d = cc2 & 63;
          const int b = r / ep.seq, t = r - b * ep.seq;
          const long bh = (long)(b * Hc + h);
          if (which == 0)      ep.h0[(bh * ep.seq + t) * Dc + d] = (half_t)(val * 0.125f); // QXs
          else if (which == 1) ep.h1[(bh * ep.seq + t) * Dc + d] = (half_t)val;            // KX
          else                 ep.h2[(bh * Dc + d) * ep.seq + t] = (half_t)val;            // VXT
        } else if constexpr (EPI == EPI_QKV_Y) {
          const float val = v + ep.bias[c];
          const int which = c >> 9;
          const int cc2 = c & 511;
          const int h = cc2 >> 6, d = cc2 & 63;
          const int b = r / ep.seq, t = r - b * ep.seq;
          const long bh = (long)(b * Hc + h);
          if (which == 0)      ep.h0[(bh * Dc + d) * ep.seq + t] = (half_t)(val * 0.125f); // QYTs
          else if (which == 1) { ep.h1[(bh * ep.seq + t) * Dc + d] = (half_t)val;          // KY
                                 ep.h3[(bh * Dc + d) * ep.seq + t] = (half_t)val; }        // KYT
          else                 ep.h2[(bh * Dc + d) * ep.seq + t] = (half_t)val;            // VYT
        } else {  // EPI_PROJ
          ep.f0[(long)r * Cc + c] = v + ep.bias[c];
        }
      }
    }
  }
}

// --------------------------------------------------------- flash body (MI=2)
// 128 q-rows/block (wave w owns rows [w*32, w*32+32), two 16-row sub-tiles).
// LDS: uni = Ks staging [128x64] UNION Ps slabs (per wave 2x 16x72, 9216
// halfs total); Vb = V^T [64][128]. Row-max via DPP; row-sum via ones-MFMA
// accumulated like O (same alpha rescale) -> no reduction shfls at all.
template <bool MASKED>
__device__ __forceinline__ void flash_body(
    const half_t* __restrict__ Qp, const half_t* __restrict__ Kp,
    const half_t* __restrict__ Vp, const unsigned char* __restrict__ mpk,
    half_t* __restrict__ outp, int Slen, int bb,
    half_t* uni, half_t* Vb)
{
  const int tid = threadIdx.x, lane = tid & 63, w = tid >> 6;
  const int r16 = lane & 15, g = lane >> 4;
  const int sIdx = bb >> 3;
  const int z = ((bb & 7) << 1) | (sIdx & 1);   // z-local per XCD
  const int q0 = (sIdx >> 1) * 128;
  const int b = z >> 3, h = z & 7;
  const int NT = Slen >> 7;
  const half_t* Qz = Qp + ((long)z * Tc + q0) * 64;
  const half_t* Kz = Kp + (long)z * Slen * 64;
  const half_t* Vz = Vp + (long)z * 64 * Slen;
  half_t* Ps[2] = { uni + w * 2304, uni + w * 2304 + 1152 };

  half8 aQ[2][2];
#pragma unroll
  for (int mi = 0; mi < 2; ++mi)
#pragma unroll
    for (int k2 = 0; k2 < 2; ++k2)
      aQ[mi][k2] = *reinterpret_cast<const half8*>(
          Qz + (w * 32 + mi * 16 + r16) * 64 + k2 * 32 + g * 8);

  half8 vones;
#pragma unroll
  for (int j = 0; j < 8; ++j) vones[j] = (half_t)1.f;

  floatx4 oacc[2][4], oaccL[2];
  float mrun[2][4];
#pragma unroll
  for (int mi = 0; mi < 2; ++mi) {
    oaccL[mi] = floatx4{0.f, 0.f, 0.f, 0.f};
#pragma unroll
    for (int no = 0; no < 4; ++no) oacc[mi][no] = floatx4{0.f, 0.f, 0.f, 0.f};
#pragma unroll
    for (int reg = 0; reg < 4; ++reg) mrun[mi][reg] = -1e30f;
  }

  for (int s0 = 0; s0 < Slen; s0 += 128) {
    // stage K [128x64] into uni, chunk swizzle js^(row&7)
#pragma unroll
    for (int i = 0; i < 4; ++i) {
      const int c = tid + i * 256;
      const int row = c >> 3, js = c & 7;
      const int jg = js ^ (row & 7);
      gld_lds16(Kz + (long)(s0 + row) * 64 + jg * 8, uni + c * 8);
    }
    // stage V^T [64x128] into Vb, chunk swizzle js^(row&15)
#pragma unroll
    for (int i = 0; i < 4; ++i) {
      const int c = tid + i * 256;
      const int row = c >> 4, js = c & 15;
      const int jg = js ^ (row & 15);
      gld_lds16(Vz + (long)row * Slen + s0 + jg * 8, Vb + c * 8);
    }
    unsigned int mb[2][4];
    if constexpr (MASKED) {
      const int tile = s0 >> 7;
#pragma unroll
      for (int mi = 0; mi < 2; ++mi)
#pragma unroll
        for (int reg = 0; reg < 4; ++reg) {
          const int t = q0 + w * 32 + mi * 16 + g * 4 + reg;
          mb[mi][reg] = mpk[((long)t * NT + tile) * 16 + r16];
        }
    }
    __syncthreads();

    // S = Q K^T : 16 b128 reads feed 32 MFMAs (shared across mi)
    floatx4 sacc[2][8];
#pragma unroll
    for (int mi = 0; mi < 2; ++mi)
#pragma unroll
      for (int ni = 0; ni < 8; ++ni) sacc[mi][ni] = floatx4{0.f, 0.f, 0.f, 0.f};
#pragma unroll
    for (int ni = 0; ni < 8; ++ni) {
      const int rB = ni * 16 + r16;
      const half8 b0 = *reinterpret_cast<const half8*>(&uni[rB * 64 + ((g) ^ (rB & 7)) * 8]);
      const half8 b1 = *reinterpret_cast<const half8*>(&uni[rB * 64 + ((4 + g) ^ (rB & 7)) * 8]);
#pragma unroll
      for (int mi = 0; mi < 2; ++mi) {
        sacc[mi][ni] = __builtin_amdgcn_mfma_f32_16x16x32_f16(aQ[mi][0], b0, sacc[mi][ni], 0, 0, 0);
        sacc[mi][ni] = __builtin_amdgcn_mfma_f32_16x16x32_f16(aQ[mi][1], b1, sacc[mi][ni], 0, 0, 0);
      }
    }
    __syncthreads();   // Ks dead -> uni becomes Ps slabs

    // mask + per-row max (DPP) + alpha rescale of O and L accumulators
    if constexpr (MASKED) {
#pragma unroll
      for (int mi = 0; mi < 2; ++mi)
#pragma unroll
        for (int reg = 0; reg < 4; ++reg)
#pragma unroll
          for (int ni = 0; ni < 8; ++ni)
            if (!((mb[mi][reg] >> ni) & 1)) sacc[mi][ni][reg] = -__builtin_inff();
    }
    float al[2][4];
#pragma unroll
    for (int mi = 0; mi < 2; ++mi)
#pragma unroll
      for (int reg = 0; reg < 4; ++reg) {
        float tm = sacc[mi][0][reg];
#pragma unroll
        for (int ni = 1; ni < 8; ++ni) tm = fmaxf(tm, sacc[mi][ni][reg]);
        tm = rowmax16(tm);
        const float mnew = fmaxf(mrun[mi][reg], tm);
        al[mi][reg] = __expf(mrun[mi][reg] - mnew);
        mrun[mi][reg] = mnew;
        oaccL[mi][reg] *= al[mi][reg];
#pragma unroll
        for (int no = 0; no < 4; ++no) oacc[mi][no][reg] *= al[mi][reg];
      }

    // exp + P write + PV (+ones row-sum MFMA), two 64-col halves
#pragma unroll
    for (int hf = 0; hf < 2; ++hf) {
#pragma unroll
      for (int mi = 0; mi < 2; ++mi)
#pragma unroll
        for (int reg = 0; reg < 4; ++reg)
#pragma unroll
          for (int ni = 0; ni < 4; ++ni) {
            const float e = __expf(sacc[mi][hf * 4 + ni][reg] - mrun[mi][reg]);
            Ps[mi][(g * 4 + reg) * 72 + ni * 16 + r16] = (half_t)e;
          }
#pragma unroll
      for (int ks2 = 0; ks2 < 2; ++ks2) {
        half8 bV[4];
#pragma unroll
        for (int no = 0; no < 4; ++no) {
          const int rV = no * 16 + r16;
          bV[no] = *reinterpret_cast<const half8*>(
              &Vb[rV * 128 + (((hf * 2 + ks2) * 4 + g) ^ (rV & 15)) * 8]);
        }
#pragma unroll
        for (int mi = 0; mi < 2; ++mi) {
          const half8 aP = *reinterpret_cast<const half8*>(
              &Ps[mi][r16 * 72 + ks2 * 32 + g * 8]);
#pragma unroll
          for (int no = 0; no < 4; ++no)
            oacc[mi][no] = __builtin_amdgcn_mfma_f32_16x16x32_f16(aP, bV[no], oacc[mi][no], 0, 0, 0);
          oaccL[mi] = __builtin_amdgcn_mfma_f32_16x16x32_f16(aP, vones, oaccL[mi], 0, 0, 0);
        }
      }
    }
    __syncthreads();   // Ps/Vb reads done -> restage
  }

  // epilogue: O/l -> out[b, t, h*64+d]; l = oaccL (all cols identical)
#pragma unroll
  for (int mi = 0; mi < 2; ++mi)
#pragma unroll
    for (int reg = 0; reg < 4; ++reg) {
      const float linv = 1.f / oaccL[mi][reg];
      const int t = q0 + w * 32 + mi * 16 + g * 4 + reg;
#pragma unroll
      for (int no = 0; no < 4; ++no) {
        const int d = no * 16 + r16;
        outp[((long)(b * Tc + t)) * Cc + h * 64 + d] = (half_t)(oacc[mi][no][reg] * linv);
      }
    }
}

// Both attentions in one launch, parity-interleaved (512 blocks).
__global__ __launch_bounds__(256) void flash_both(
    const half_t* __restrict__ Q2, const half_t* __restrict__ KX,
    const half_t* __restrict__ VXT, const unsigned char* __restrict__ mpk,
    half_t* __restrict__ CV2,
    const half_t* __restrict__ QX, const half_t* __restrict__ KY,
    const half_t* __restrict__ VYT, half_t* __restrict__ DH2)
{
  __shared__ __align__(16) half_t uni[9216];
  __shared__ __align__(16) half_t Vb[8192];
  const int bx = blockIdx.x;
  if ((bx & 1) == 0)
    flash_body<true>(Q2, KX, VXT, mpk, CV2, Tc, bx >> 1, uni, Vb);
  else
    flash_body<false>(QX, KY, VYT, nullptr, DH2, Mc, bx >> 1, uni, Vb);
}

// ----------------------------------------------- prep: converts + mask pack
__device__ __forceinline__ void cvt4(const float* in, half_t* out, long i) {
  const float4 f = reinterpret_cast<const float4*>(in)[i];
  half4v h; h[0] = (half_t)f.x; h[1] = (half_t)f.y; h[2] = (half_t)f.z; h[3] = (half_t)f.w;
  reinterpret_cast<half4v*>(out)[i] = h;
}

__global__ __launch_bounds__(256) void prep(
    const float* __restrict__ x, const float* __restrict__ y,
    const float* __restrict__ qw, const float* __restrict__ pw,
    const int* __restrict__ mask,
    half_t* __restrict__ XH, half_t* __restrict__ YH,
    half_t* __restrict__ WQ, half_t* __restrict__ WP,
    unsigned char* __restrict__ mpk)
{
  const long i = (long)blockIdx.x * 256 + threadIdx.x;
  constexpr long n0 = 524288;            // x/4
  constexpr long n1 = n0 + 262144;       // y/4
  constexpr long n2 = n1 + 196608;       // qkv_w/4
  constexpr long n3 = n2 + 65536;        // proj_w/4
  if (i < n0) cvt4(x, XH, i);
  else if (i < n1) cvt4(y, YH, i - n0);
  else if (i < n2) cvt4(qw, WQ, i - n1);
  else if (i < n3) cvt4(pw, WP, i - n2);
  else {
    const long idx = i - n3;             // [0, Tc*256)
    const int t = (int)(idx >> 8), tile = (int)((idx >> 4) & 15), r16 = (int)(idx & 15);
    const int* row = mask + (long)t * Tc + tile * 128 + r16;
    unsigned int bbits = 0;
#pragma unroll
    for (int ni = 0; ni < 8; ++ni)
      bbits |= (row[ni * 16] != 0 ? 1u : 0u) << ni;
    mpk[idx] = (unsigned char)bbits;
  }
}

// ------------------------------------------------------- DH = DH2 - CV2
__global__ __launch_bounds__(256) void diff_k(
    const half_t* __restrict__ a, const half_t* __restrict__ b,
    half_t* __restrict__ o)
{
  const long i = (long)blockIdx.x * 256 + threadIdx.x;
  const half8 va = reinterpret_cast<const half8*>(a)[i];
  const half8 vb = reinterpret_cast<const half8*>(b)[i];
  reinterpret_cast<half8*>(o)[i] = va - vb;
}

// ------------------------------------------------------------- workspace map
constexpr size_t OFF_XH   = 0;                                   // [B*T,C] f16
constexpr size_t OFF_YH   = OFF_XH   + (size_t)Bc*Tc*Cc*2;
constexpr size_t OFF_WQ   = OFF_YH   + (size_t)Bc*Mc*Cc*2;
constexpr size_t OFF_WP   = OFF_WQ   + (size_t)3*Cc*Cc*2;
constexpr size_t OFF_QX   = OFF_WP   + (size_t)Cc*Cc*2;          // [z,T,D] scaled
constexpr size_t OFF_KX   = OFF_QX   + (size_t)Bc*Hc*Tc*Dc*2;    // [z,T,D]
constexpr size_t OFF_VXT  = OFF_KX   + (size_t)Bc*Hc*Tc*Dc*2;    // [z,D,T]
constexpr size_t OFF_QYT  = OFF_VXT  + (size_t)Bc*Hc*Tc*Dc*2;    // [z,D,M] scaled
constexpr size_t OFF_KY   = OFF_QYT  + (size_t)Bc*Hc*Mc*Dc*2;    // [z,M,D]
constexpr size_t OFF_KYT  = OFF_KY   + (size_t)Bc*Hc*Mc*Dc*2;    // [z,D,M]
constexpr size_t OFF_VYT  = OFF_KYT  + (size_t)Bc*Hc*Mc*Dc*2;    // [z,D,M]
constexpr size_t OFF_WT   = OFF_VYT  + (size_t)Bc*Hc*Mc*Dc*2;    // [z,64,64]
constexpr size_t OFF_Q2   = OFF_WT   + (size_t)Bc*Hc*Dc*Dc*2;    // [z,T,D]
constexpr size_t OFF_CV2  = OFF_Q2   + (size_t)Bc*Hc*Tc*Dc*2;    // [B,T,C]
constexpr size_t OFF_DH2  = OFF_CV2  + (size_t)Bc*Tc*Cc*2;       // [B,T,C] raw cval_x2y
constexpr size_t OFF_DH   = OFF_DH2  + (size_t)Bc*Tc*Cc*2;       // [B,T,C] diff
constexpr size_t OFF_MPK  = OFF_DH   + (size_t)Bc*Tc*Cc*2;       // [T,16,16] u8
// total ~54 MB

extern "C" void kernel_launch(void* const* d_in, const int* in_sizes, int n_in,
                              void* d_out, int out_size, void* d_ws, size_t ws_size,
                              hipStream_t stream) {
  const float* x      = (const float*)d_in[0];
  const float* y      = (const float*)d_in[1];
  const int*   mask   = (const int*)  d_in[2];
  const float* qkv_b  = (const float*)d_in[4];
  const float* proj_b = (const float*)d_in[6];
  float* out = (float*)d_out;
  char* ws = (char*)d_ws;

  half_t* XH   = (half_t*)(ws + OFF_XH);
  half_t* YH   = (half_t*)(ws + OFF_YH);
  half_t* WQ   = (half_t*)(ws + OFF_WQ);
  half_t* WP   = (half_t*)(ws + OFF_WP);
  half_t* QX   = (half_t*)(ws + OFF_QX);
  half_t* KX   = (half_t*)(ws + OFF_KX);
  half_t* VXT  = (half_t*)(ws + OFF_VXT);
  half_t* QYT  = (half_t*)(ws + OFF_QYT);
  half_t* KY   = (half_t*)(ws + OFF_KY);
  half_t* KYT  = (half_t*)(ws + OFF_KYT);
  half_t* VYT  = (half_t*)(ws + OFF_VYT);
  half_t* WT   = (half_t*)(ws + OFF_WT);
  half_t* Q2   = (half_t*)(ws + OFF_Q2);
  half_t* CV2  = (half_t*)(ws + OFF_CV2);
  half_t* DH2  = (half_t*)(ws + OFF_DH2);
  half_t* DH   = (half_t*)(ws + OFF_DH);
  unsigned char* MPK = (unsigned char*)(ws + OFF_MPK);

  // converts + mask packing (one launch)
  prep<<<6144, 256, 0, stream>>>(x, y, (const float*)d_in[3], (const float*)d_in[5],
                                 mask, XH, YH, WQ, WP, MPK);

  // qkv projections
  {
    EpiParams ep{}; ep.h0 = QX; ep.h1 = KX; ep.h2 = VXT; ep.bias = qkv_b; ep.seq = Tc;
    gemm_nt<128,128,2,2,EPI_QKV_X><<<dim3(12, 32, 1), 256, 0, stream>>>(
        XH, WQ, Cc, Cc, Cc, 0, 0, ep);
  }
  {
    EpiParams ep{}; ep.h0 = QYT; ep.h1 = KY; ep.h2 = VYT; ep.h3 = KYT;
    ep.bias = qkv_b; ep.seq = Mc;
    gemm_nt<64,128,2,2,EPI_QKV_Y><<<dim3(12, 32, 1), 256, 0, stream>>>(
        YH, WQ, Cc, Cc, Cc, 0, 0, ep);
  }

  // WT[z][d2][d1] = 0.125 * sum_m QYTs[d2,m] KYT[d1,m]  (total scale^3)
  {
    EpiParams ep{}; ep.h0 = WT; ep.scale = 0.125f; ep.ldc = 64; ep.bstride = 64 * 64;
    gemm_nt<64,64,2,2,EPI_F16STORE><<<dim3(1, 1, Bc*Hc), 256, 0, stream>>>(
        QYT, KYT, Mc, Mc, Mc, (long)Dc*Mc, (long)Dc*Mc, ep);
  }
  // Q2[z][t][d2] = sum_d1 QXs[t,d1] WT[d2,d1]
  {
    EpiParams ep{}; ep.h0 = Q2; ep.scale = 1.f; ep.ldc = 64; ep.bstride = (long)Tc * 64;
    gemm_nt<128,64,2,2,EPI_F16STORE><<<dim3(1, Tc/128, Bc*Hc), 256, 0, stream>>>(
        QX, WT, Dc, Dc, Dc, (long)Tc*Dc, (long)64*64, ep);
  }

  // both attentions, one launch (parity-interleaved, 512 blocks, MI=2)
  flash_both<<<dim3(2 * (Tc/128) * Bc*Hc), 256, 0, stream>>>(
      Q2, KX, VXT, MPK, CV2, QX, KY, VYT, DH2);

  // DH = cval_x2y - cval_y2x
  diff_k<<<(int)(BTC/8/256), 256, 0, stream>>>(DH2, CV2, DH);

  // out = DH @ proj_w^T + proj_b
  {
    EpiParams ep{}; ep.f0 = out; ep.bias = proj_b;
    gemm_nt<128,64,2,2,EPI_PROJ><<<dim3(8, 32, 1), 256, 0, stream>>>(
        DH, WP, Cc, Cc, Cc, 0, 0, ep);
  }
}